// Round 9
// baseline (412.251 us; speedup 1.0000x reference)
//
#include <hip/hip_runtime.h>
#include <cmath>

// ---------------------------------------------------------------------------
// GNNPooling: 3x (ChebConv -> BN(train) -> ReLU) -> mean over nodes.
// Lhat = alpha*I + beta*J  =>  y[b] = A_b @ WI + 1 * colsum(A_b @ WJ)
// Round 9: SWAPPED GEMM y^T = WI^T @ h^T: A-operand = W granules (same bits
// as before), B-operand = h fragments (same bits as before), so the C/D
// output (lane = 4 channel-rows x 1 node-col) stores DIRECTLY to global as
// packed 8B bf16 chunks -- no LDS transpose at all. Next layer reads its
// fragments as two 8B chunks per lane. BN stats via in-wave butterflies +
// per-block atomicAdd into raw[256]; consumers compute scale/shift in their
// prologue (finA/finB kernels deleted). 512-thr blocks: L1 8 waves/CU,
// L2/3 2 blocks/CU = 16 waves/CU.
// y chunk layout per batch: chunk[(ct*4+nt)*64 + lk*16 + node] (8B) holds
// y[node + nt*16][ct*16 + lk*4 + r], r=0..3.
// ---------------------------------------------------------------------------

typedef __attribute__((ext_vector_type(8))) short bf16x8;
typedef __attribute__((ext_vector_type(4))) float f32x4;

typedef __attribute__((address_space(1))) const unsigned int guint_t;
typedef __attribute__((address_space(3))) unsigned int luint_t;

constexpr int BATCH = 4096;
constexpr int DCH   = 128;
constexpr float INV_NROWS = 1.0f / 262144.0f;

// workspace offsets (in floats)
constexpr size_t OFF_G1   = 0;            // layer1 WI+WJ granules: 32768 floats
constexpr size_t OFF_G2   = 32768;        // 16384 floats
constexpr size_t OFF_G3   = 49152;        // 16384 floats
constexpr size_t OFF_RAW  = 65536;        // 3 * 256 stat accumulators
constexpr size_t OFF_Y    = 1180416;      // y bf16 chunks: 4096*8192 ushorts

struct Coeffs { float a[5]; float b[5]; };

__device__ __forceinline__ unsigned short f2bf(float f) {
  unsigned u = __float_as_uint(f);
  u += 0x7FFFu + ((u >> 16) & 1u);        // round-to-nearest-even
  return (unsigned short)(u >> 16);
}
__device__ __forceinline__ float bf2f(unsigned short s) {
  return __uint_as_float(((unsigned)s) << 16);
}
__device__ __forceinline__ unsigned packbf(float lo, float hi) {
  return (unsigned)f2bf(lo) | ((unsigned)f2bf(hi) << 16);
}

// ---------------------------------------------------------------------------
// prep_gran: WI (= sum_k a_k W_k) and WJ (= sum_k b_k W_k) granules, bf16.
// unit r = kt*512 + ct*64 + lane holds W[kt*32+(lane>>4)*8+i][ct*16+(lane&15)]
// (serves as the W^T A-fragment in the swapped GEMM). Also zeros raw[768].
// ---------------------------------------------------------------------------
__global__ __launch_bounds__(256) void prep_gran(const float* __restrict__ W1,
                                                 const float* __restrict__ W2,
                                                 const float* __restrict__ W3,
                                                 float* __restrict__ ws,
                                                 float* __restrict__ raw, Coeffs co)
{
  if (blockIdx.x == 0) {
    raw[threadIdx.x]       = 0.f;
    raw[256 + threadIdx.x] = 0.f;
    raw[512 + threadIdx.x] = 0.f;
  }
  int id = blockIdx.x * 256 + threadIdx.x;       // 0..16383
  const float* W; int CIN, K, r; const float* cf; unsigned short* dst;
  if (id < 8192) {
    W = W1; CIN = 256; K = 5; r = id & 4095;
    cf = (id >= 4096) ? co.b : co.a;
    dst = (unsigned short*)(ws + OFF_G1) + (size_t)id * 8;
  } else if (id < 12288) {
    int e = id - 8192; W = W2; CIN = 128; K = 3; r = e & 2047;
    cf = (e >= 2048) ? co.b : co.a;
    dst = (unsigned short*)(ws + OFF_G2) + (size_t)e * 8;
  } else {
    int e = id - 12288; W = W3; CIN = 128; K = 3; r = e & 2047;
    cf = (e >= 2048) ? co.b : co.a;
    dst = (unsigned short*)(ws + OFF_G3) + (size_t)e * 8;
  }
  int kt  = r >> 9;
  int ct  = (r >> 6) & 7;
  int ln  = r & 63;
  int col = ct * 16 + (ln & 15);
  int f0  = kt * 32 + (ln >> 4) * 8;
  bf16x8 g;
#pragma unroll
  for (int i = 0; i < 8; ++i) {
    float s = 0.f;
    for (int k = 0; k < K; ++k)
      s = fmaf(cf[k], W[((size_t)k * CIN + f0 + i) * DCH + col], s);
    g[i] = (short)f2bf(s);
  }
  *reinterpret_cast<bf16x8*>(dst) = g;
}

// ---------------------------------------------------------------------------
// Fused layer: 512 threads = 8 waves; wave owns one batch per iteration
// (all 64 nodes). B (W granules) staged in LDS once per block.
// ---------------------------------------------------------------------------
template <int CIN, bool FIRST, int ITERS>
__global__ __launch_bounds__(512, 2) void layer_k(
    const float* __restrict__ inF,              // FIRST: x (row-major fp32)
    const unsigned short* __restrict__ inB,     // !FIRST: y bf16 chunks
    unsigned short* __restrict__ yout,          // y bf16 chunks
    const unsigned short* __restrict__ gran,    // WI then WJ granules (bf16)
    const float* __restrict__ rawIn,            // prev-layer stats or null
    const float* __restrict__ gam, const float* __restrict__ bet,
    float* __restrict__ rawOut)                 // this layer's stat accumulator
{
  constexpr int NKT = CIN / 32;
  constexpr int NG  = CIN * 16;                 // bf16x8 units per matrix

  __shared__ unsigned short sB[CIN * 256];      // WI+WJ granules (CIN*512 B)
  __shared__ float sRed[8][256];                // per-wave stat accum
  __shared__ float sScale[DCH];
  __shared__ float sShift[DCH];

  const int tid  = threadIdx.x;
  const int wv   = tid >> 6;           // 0..7
  const int l    = tid & 63;
  const int node = l & 15;
  const int lk   = l >> 4;

  // ---- stage B once: linear global_load_lds, 8 waves x 1KB per round ----
  {
    const char* gB = reinterpret_cast<const char*>(gran);
    char* lB = reinterpret_cast<char*>(&sB[0]);
#pragma unroll
    for (int i = 0; i < (CIN * 512) / 8192; ++i) {
      const int c = i * 8 + wv;
      __builtin_amdgcn_global_load_lds(
          (guint_t*)(gB + (size_t)c * 1024 + (size_t)l * 16),
          (luint_t*)(lB + c * 1024), 16, 0, 0);
    }
  }
  if constexpr (!FIRST) {
    if (tid < DCH) {
      float mu  = rawIn[tid] * INV_NROWS;
      float var = rawIn[DCH + tid] * INV_NROWS - mu * mu;
      float rs  = rsqrtf(var + 1e-5f);
      float sc  = gam[tid] * rs;
      sScale[tid] = sc;
      sShift[tid] = fmaf(-mu, sc, bet[tid]);
    }
  }
  __syncthreads();                              // drains staging

  const bf16x8* sBu = reinterpret_cast<const bf16x8*>(&sB[0]);

#pragma unroll 1
  for (int it = 0; it < ITERS; ++it) {
    const int batch = blockIdx.x * (8 * ITERS) + it * 8 + wv;

    f32x4 acc[8][4];                            // [ct(channel-tile)][nt(node-tile)]
    f32x4 accJ[8];
#pragma unroll
    for (int ct = 0; ct < 8; ++ct) {
#pragma unroll
      for (int nt = 0; nt < 4; ++nt)
#pragma unroll
        for (int r = 0; r < 4; ++r) acc[ct][nt][r] = 0.f;
#pragma unroll
      for (int r = 0; r < 4; ++r) accJ[ct][r] = 0.f;
    }

#pragma unroll
    for (int kt = 0; kt < NKT; ++kt) {
      bf16x8 af[4];                             // h-fragments per node-tile
      float vs[8];
#pragma unroll
      for (int i = 0; i < 8; ++i) vs[i] = 0.f;

      if constexpr (FIRST) {
        const float* ap = inF + ((size_t)batch * 64 + node) * CIN + kt * 32 + lk * 8;
#pragma unroll
        for (int nt = 0; nt < 4; ++nt) {
          float4 u0 = *reinterpret_cast<const float4*>(ap + (size_t)nt * 16 * CIN);
          float4 u1 = *reinterpret_cast<const float4*>(ap + (size_t)nt * 16 * CIN + 4);
          float v8[8] = {u0.x, u0.y, u0.z, u0.w, u1.x, u1.y, u1.z, u1.w};
#pragma unroll
          for (int i = 0; i < 8; ++i) {
            vs[i] += v8[i];
            af[nt][i] = (short)f2bf(v8[i]);
          }
        }
      } else {
        const int c0 = kt * 32 + lk * 8;
        const float4 s0 = *reinterpret_cast<const float4*>(&sScale[c0]);
        const float4 s1 = *reinterpret_cast<const float4*>(&sScale[c0 + 4]);
        const float4 h0 = *reinterpret_cast<const float4*>(&sShift[c0]);
        const float4 h1 = *reinterpret_cast<const float4*>(&sShift[c0 + 4]);
        const float scv[8] = {s0.x, s0.y, s0.z, s0.w, s1.x, s1.y, s1.z, s1.w};
        const float shv[8] = {h0.x, h0.y, h0.z, h0.w, h1.x, h1.y, h1.z, h1.w};
        const uint2* yb = reinterpret_cast<const uint2*>(inB + (size_t)batch * 8192);
        const int ct_src = 2 * kt + (lk >> 1);
        const int lks    = 2 * (lk & 1);
#pragma unroll
        for (int nt = 0; nt < 4; ++nt) {
          uint2 g0 = yb[(ct_src * 4 + nt) * 64 + lks * 16 + node];
          uint2 g1 = yb[(ct_src * 4 + nt) * 64 + (lks + 1) * 16 + node];
          unsigned short u8[8] = {
            (unsigned short)(g0.x & 0xffff), (unsigned short)(g0.x >> 16),
            (unsigned short)(g0.y & 0xffff), (unsigned short)(g0.y >> 16),
            (unsigned short)(g1.x & 0xffff), (unsigned short)(g1.x >> 16),
            (unsigned short)(g1.y & 0xffff), (unsigned short)(g1.y >> 16)};
#pragma unroll
          for (int i = 0; i < 8; ++i) {
            float hv = fmaxf(fmaf(bf2f(u8[i]), scv[i], shv[i]), 0.f);
            vs[i] += hv;
            af[nt][i] = (short)f2bf(hv);
          }
        }
      }

      bf16x8 asum;
#pragma unroll
      for (int i = 0; i < 8; ++i) asum[i] = (short)f2bf(vs[i]);

#pragma unroll
      for (int ct = 0; ct < 8; ++ct) {
        bf16x8 fI = sBu[kt * 512 + ct * 64 + l];
#pragma unroll
        for (int nt = 0; nt < 4; ++nt)
          acc[ct][nt] = __builtin_amdgcn_mfma_f32_16x16x32_bf16(fI, af[nt], acc[ct][nt], 0, 0, 0);
      }
#pragma unroll
      for (int ct = 0; ct < 8; ++ct) {
        bf16x8 fJ = sBu[NG + kt * 512 + ct * 64 + l];
        accJ[ct] = __builtin_amdgcn_mfma_f32_16x16x32_bf16(fJ, asum, accJ[ct], 0, 0, 0);
      }
    }

    // jv: sum accJ over the 16 pseudo-node cols -> accJ[ct][r] = jrow[ct*16+lk*4+r]
#pragma unroll
    for (int ct = 0; ct < 8; ++ct)
#pragma unroll
      for (int m = 1; m <= 8; m <<= 1)
#pragma unroll
        for (int r = 0; r < 4; ++r)
          accJ[ct][r] += __shfl_xor(accJ[ct][r], m);

    // ---- epilogue: direct packed stores + in-wave stat butterflies ----
    uint2* yo = reinterpret_cast<uint2*>(yout + (size_t)batch * 8192);
#pragma unroll
    for (int ct = 0; ct < 8; ++ct) {
      f32x4 sv, qv;
#pragma unroll
      for (int r = 0; r < 4; ++r) { sv[r] = 0.f; qv[r] = 0.f; }
#pragma unroll
      for (int nt = 0; nt < 4; ++nt) {
        float v0 = acc[ct][nt][0] + accJ[ct][0];
        float v1 = acc[ct][nt][1] + accJ[ct][1];
        float v2 = acc[ct][nt][2] + accJ[ct][2];
        float v3 = acc[ct][nt][3] + accJ[ct][3];
        sv[0] += v0; qv[0] = fmaf(v0, v0, qv[0]);
        sv[1] += v1; qv[1] = fmaf(v1, v1, qv[1]);
        sv[2] += v2; qv[2] = fmaf(v2, v2, qv[2]);
        sv[3] += v3; qv[3] = fmaf(v3, v3, qv[3]);
        uint2 st;
        st.x = packbf(v0, v1);
        st.y = packbf(v2, v3);
        yo[(ct * 4 + nt) * 64 + l] = st;
      }
#pragma unroll
      for (int m = 1; m <= 8; m <<= 1)
#pragma unroll
        for (int r = 0; r < 4; ++r) {
          sv[r] += __shfl_xor(sv[r], m);
          qv[r] += __shfl_xor(qv[r], m);
        }
      if (node == 0) {
        f32x4* ps = reinterpret_cast<f32x4*>(&sRed[wv][ct * 16 + lk * 4]);
        f32x4* pq = reinterpret_cast<f32x4*>(&sRed[wv][128 + ct * 16 + lk * 4]);
        if (it == 0) { *ps = sv; *pq = qv; }
        else         { *ps = *ps + sv; *pq = *pq + qv; }
      }
    }
  }

  __syncthreads();
  if (tid < 256) {
    float tot = 0.f;
#pragma unroll
    for (int w2 = 0; w2 < 8; ++w2) tot += sRed[w2][tid];
    atomicAdd(&rawOut[tid], tot);
  }
}

// ---------------------------------------------------------------------------
// Final BN + ReLU + mean over nodes (reads bf16 chunks, scsh from raw inline)
// ---------------------------------------------------------------------------
__global__ __launch_bounds__(256) void pool_k(const unsigned short* __restrict__ y,
                                              const float* __restrict__ raw,
                                              const float* __restrict__ gam,
                                              const float* __restrict__ bet,
                                              float* __restrict__ out)
{
  const int b  = blockIdx.x;
  const int t  = threadIdx.x;
  const int ct = t >> 5, lk = (t >> 3) & 3, n0 = t & 7;
  const int ch0 = ct * 16 + lk * 4;

  float4 rs_ = *reinterpret_cast<const float4*>(&raw[ch0]);
  float4 rq_ = *reinterpret_cast<const float4*>(&raw[128 + ch0]);
  float4 g4  = *reinterpret_cast<const float4*>(&gam[ch0]);
  float4 b4  = *reinterpret_cast<const float4*>(&bet[ch0]);
  float sc[4], sh[4];
  {
    const float rsv[4] = {rs_.x, rs_.y, rs_.z, rs_.w};
    const float rqv[4] = {rq_.x, rq_.y, rq_.z, rq_.w};
    const float gv[4]  = {g4.x, g4.y, g4.z, g4.w};
    const float bv[4]  = {b4.x, b4.y, b4.z, b4.w};
#pragma unroll
    for (int r = 0; r < 4; ++r) {
      float mu  = rsv[r] * INV_NROWS;
      float var = rqv[r] * INV_NROWS - mu * mu;
      float rr  = rsqrtf(var + 1e-5f);
      sc[r] = gv[r] * rr;
      sh[r] = fmaf(-mu, sc[r], bv[r]);
    }
  }

  const uint2* yb = reinterpret_cast<const uint2*>(y + (size_t)b * 8192);
  float s[4] = {0.f, 0.f, 0.f, 0.f};
#pragma unroll
  for (int nt = 0; nt < 4; ++nt)
#pragma unroll
    for (int nn = 0; nn < 2; ++nn) {
      const int nd = n0 + nn * 8;
      uint2 g = yb[(ct * 4 + nt) * 64 + lk * 16 + nd];
      float v0 = bf2f((unsigned short)(g.x & 0xffff));
      float v1 = bf2f((unsigned short)(g.x >> 16));
      float v2 = bf2f((unsigned short)(g.y & 0xffff));
      float v3 = bf2f((unsigned short)(g.y >> 16));
      s[0] += fmaxf(fmaf(v0, sc[0], sh[0]), 0.f);
      s[1] += fmaxf(fmaf(v1, sc[1], sh[1]), 0.f);
      s[2] += fmaxf(fmaf(v2, sc[2], sh[2]), 0.f);
      s[3] += fmaxf(fmaf(v3, sc[3], sh[3]), 0.f);
    }
#pragma unroll
  for (int m = 1; m <= 4; m <<= 1)
#pragma unroll
    for (int r = 0; r < 4; ++r) s[r] += __shfl_xor(s[r], m);

  if (n0 == 0) {
    float4 o = make_float4(s[0] * (1.0f / 64.0f), s[1] * (1.0f / 64.0f),
                           s[2] * (1.0f / 64.0f), s[3] * (1.0f / 64.0f));
    *reinterpret_cast<float4*>(&out[(size_t)b * DCH + ch0]) = o;
  }
}

// ---------------------------------------------------------------------------
extern "C" void kernel_launch(void* const* d_in, const int* in_sizes, int n_in,
                              void* d_out, int out_size, void* d_ws, size_t ws_size,
                              hipStream_t stream)
{
  const float* x  = (const float*)d_in[0];
  const float* W1 = (const float*)d_in[1];
  const float* W2 = (const float*)d_in[2];
  const float* W3 = (const float*)d_in[3];
  const float* g1 = (const float*)d_in[4];
  const float* b1 = (const float*)d_in[5];
  const float* g2 = (const float*)d_in[6];
  const float* b2 = (const float*)d_in[7];
  const float* g3 = (const float*)d_in[8];
  const float* b3 = (const float*)d_in[9];
  float* out = (float*)d_out;
  float* ws  = (float*)d_ws;

  Coeffs co;
  {
    double sd  = sqrt(63.0 / 4095.0);
    double av  = exp(-1.0 / sd);
    double deg = 1.0 + 63.0 * av;
    double al  = -(1.0 - av) / deg;
    double be  = -av / deg;
    double ak[5], bk[5];
    ak[0] = 1.0; bk[0] = 0.0;
    ak[1] = al;  bk[1] = be;
    for (int k = 2; k < 5; ++k) {
      ak[k] = 2.0 * al * ak[k - 1] - ak[k - 2];
      bk[k] = 2.0 * (be * ak[k - 1] + (al + 64.0 * be) * bk[k - 1]) - bk[k - 2];
    }
    for (int k = 0; k < 5; ++k) { co.a[k] = (float)ak[k]; co.b[k] = (float)bk[k]; }
  }

  const unsigned short* gr1 = (const unsigned short*)(ws + OFF_G1);
  const unsigned short* gr2 = (const unsigned short*)(ws + OFF_G2);
  const unsigned short* gr3 = (const unsigned short*)(ws + OFF_G3);
  float* raw1 = ws + OFF_RAW;
  float* raw2 = raw1 + 256;
  float* raw3 = raw1 + 512;
  unsigned short* yv = (unsigned short*)(ws + OFF_Y);

  prep_gran<<<64, 256, 0, stream>>>(W1, W2, W3, ws, raw1, co);

  layer_k<256, true, 2><<<256, 512, 0, stream>>>(x, nullptr, yv, gr1,
                                                 nullptr, nullptr, nullptr, raw1);
  layer_k<128, false, 1><<<512, 512, 0, stream>>>(nullptr, yv, yv, gr2,
                                                  raw1, g1, b1, raw2);
  layer_k<128, false, 1><<<512, 512, 0, stream>>>(nullptr, yv, yv, gr3,
                                                  raw2, g2, b2, raw3);
  pool_k<<<BATCH, 256, 0, stream>>>(yv, raw3, g3, b3, out);

  (void)in_sizes; (void)n_in; (void)out_size; (void)ws_size;
}

// Round 10
// 227.441 us; speedup vs baseline: 1.8126x; 1.8126x over previous
//
#include <hip/hip_runtime.h>
#include <cmath>

// ---------------------------------------------------------------------------
// GNNPooling: 3x (ChebConv -> BN(train) -> ReLU) -> mean over nodes.
// Lhat = alpha*I + beta*J  =>  y[b] = A_b @ WI + 1 * colsum(A_b @ WJ)
// Round 10 = Round 8 structure (best, 217us) + three surgical changes:
//  1) BN stats via register accumulation + 2 shuffles + one atomicAdd/block
//     into raw[256] (finA/finB kernels deleted; prep zeros raws).
//  2) Occupancy x2: L1 = 512-thr blocks (8 waves, 2 waves/SIMD, ~155KB LDS,
//     two-pass 16x72 epilogue slab); L2/3 = 256-thr blocks at ~78KB LDS ->
//     2 blocks/CU.
//  3) __launch_bounds__(threads) ONLY -- no min-waves arg (R7/R9 proved it
//     forces 128 VGPR and spills the 160-reg accumulator).
// ---------------------------------------------------------------------------

typedef __attribute__((ext_vector_type(8))) short bf16x8;
typedef __attribute__((ext_vector_type(4))) float f32x4;

typedef __attribute__((address_space(1))) const unsigned int guint_t;
typedef __attribute__((address_space(3))) unsigned int luint_t;

constexpr int BATCH = 4096;
constexpr int DCH   = 128;
constexpr float INV_NROWS = 1.0f / 262144.0f;

// workspace offsets (in floats)
constexpr size_t OFF_G1   = 0;            // layer1 WI+WJ granules: 32768 floats
constexpr size_t OFF_G2   = 32768;        // 16384 floats
constexpr size_t OFF_G3   = 49152;        // 16384 floats
constexpr size_t OFF_RAW  = 65536;        // 3*256 stat accumulators
constexpr size_t OFF_Y    = 1180416;      // y bf16 granules: 4096*8192 ushorts

struct Coeffs { float a[5]; float b[5]; };

__device__ __forceinline__ unsigned short f2bf(float f) {
  unsigned u = __float_as_uint(f);
  u += 0x7FFFu + ((u >> 16) & 1u);        // round-to-nearest-even
  return (unsigned short)(u >> 16);
}
__device__ __forceinline__ float bf2f(unsigned short s) {
  return __uint_as_float(((unsigned)s) << 16);
}

// ---------------------------------------------------------------------------
// prep_gran: WI (= sum_k a_k W_k) and WJ (= sum_k b_k W_k) in B-fragment
// granule order, bf16. unit r = kt*512 + ct*64 + lane holds 8 values
// W[kt*32+(lane>>4)*8+i][ct*16+(lane&15)]. Also zeros raw[768].
// ---------------------------------------------------------------------------
__global__ __launch_bounds__(256) void prep_gran(const float* __restrict__ W1,
                                                 const float* __restrict__ W2,
                                                 const float* __restrict__ W3,
                                                 float* __restrict__ ws,
                                                 float* __restrict__ raw, Coeffs co)
{
  if (blockIdx.x == 0) {
    raw[threadIdx.x]       = 0.f;
    raw[256 + threadIdx.x] = 0.f;
    raw[512 + threadIdx.x] = 0.f;
  }
  int id = blockIdx.x * 256 + threadIdx.x;       // 0..16383
  const float* W; int CIN, K, r; const float* cf; unsigned short* dst;
  if (id < 8192) {
    W = W1; CIN = 256; K = 5; r = id & 4095;
    cf = (id >= 4096) ? co.b : co.a;
    dst = (unsigned short*)(ws + OFF_G1) + (size_t)id * 8;
  } else if (id < 12288) {
    int e = id - 8192; W = W2; CIN = 128; K = 3; r = e & 2047;
    cf = (e >= 2048) ? co.b : co.a;
    dst = (unsigned short*)(ws + OFF_G2) + (size_t)e * 8;
  } else {
    int e = id - 12288; W = W3; CIN = 128; K = 3; r = e & 2047;
    cf = (e >= 2048) ? co.b : co.a;
    dst = (unsigned short*)(ws + OFF_G3) + (size_t)e * 8;
  }
  int kt  = r >> 9;
  int ct  = (r >> 6) & 7;
  int ln  = r & 63;
  int col = ct * 16 + (ln & 15);
  int f0  = kt * 32 + (ln >> 4) * 8;
  bf16x8 g;
#pragma unroll
  for (int i = 0; i < 8; ++i) {
    float s = 0.f;
    for (int k = 0; k < K; ++k)
      s = fmaf(cf[k], W[((size_t)k * CIN + f0 + i) * DCH + col], s);
    g[i] = (short)f2bf(s);
  }
  *reinterpret_cast<bf16x8*>(dst) = g;
}

// ---------------------------------------------------------------------------
// Fused layer: NW waves; wave owns one batch per iteration (all 64 nodes).
// B (WI+WJ granules) staged in LDS once per block via global_load_lds.
// ---------------------------------------------------------------------------
template <int CIN, bool FIRST, int ITERS, int NW>
__global__ __launch_bounds__(NW * 64) void layer_k(
    const float* __restrict__ inF,              // FIRST: x (row-major fp32)
    const unsigned short* __restrict__ inB,     // !FIRST: y bf16 granules
    unsigned short* __restrict__ yout,          // y bf16 granules
    const unsigned short* __restrict__ gran,    // WI then WJ granules (bf16)
    const float* __restrict__ rawIn,            // prev-layer stats or null
    const float* __restrict__ gam, const float* __restrict__ bet,
    float* __restrict__ rawOut)                 // this layer's stat accumulator
{
  constexpr int NKT = CIN / 32;
  constexpr int NG  = CIN * 16;                 // bf16x8 units per matrix

  __shared__ unsigned short sB[CIN * 256];      // WI+WJ granules (CIN*512 B)
  __shared__ unsigned short sT[NW][16 * 72];    // per-wave two-pass transpose
  __shared__ float sRed[NW][256];               // per-wave stat partials
  __shared__ float sScale[DCH];
  __shared__ float sShift[DCH];

  const int tid = threadIdx.x;
  const int wv  = tid >> 6;
  const int l   = tid & 63;
  const int lr  = l & 15;
  const int lk  = l >> 4;

  // ---- stage B once: linear global_load_lds, NW waves x 1KB per round ----
  {
    const char* gB = reinterpret_cast<const char*>(gran);
    char* lB = reinterpret_cast<char*>(&sB[0]);
#pragma unroll
    for (int i = 0; i < (CIN * 512) / (NW * 1024); ++i) {
      const int c = i * NW + wv;
      __builtin_amdgcn_global_load_lds(
          (guint_t*)(gB + (size_t)c * 1024 + (size_t)l * 16),
          (luint_t*)(lB + c * 1024), 16, 0, 0);
    }
  }
  if constexpr (!FIRST) {
    if (tid < DCH) {
      float mu  = rawIn[tid] * INV_NROWS;
      float var = rawIn[DCH + tid] * INV_NROWS - mu * mu;
      float rs  = rsqrtf(var + 1e-5f);
      float sc  = gam[tid] * rs;
      sScale[tid] = sc;
      sShift[tid] = fmaf(-mu, sc, bet[tid]);
    }
  }
  __syncthreads();                              // drains staging

  const bf16x8* sBu = reinterpret_cast<const bf16x8*>(&sB[0]);

  float psum[8], psq[8];                        // per-lane stats across ITERS
#pragma unroll
  for (int ct = 0; ct < 8; ++ct) { psum[ct] = 0.f; psq[ct] = 0.f; }

#pragma unroll 1
  for (int it = 0; it < ITERS; ++it) {
    const int batch = blockIdx.x * (NW * ITERS) + it * NW + wv;

    f32x4 acc[8][4];                            // [ct][mt]
    f32x4 accJ[8];
#pragma unroll
    for (int ct = 0; ct < 8; ++ct) {
#pragma unroll
      for (int mt = 0; mt < 4; ++mt)
#pragma unroll
        for (int r = 0; r < 4; ++r) acc[ct][mt][r] = 0.f;
#pragma unroll
      for (int r = 0; r < 4; ++r) accJ[ct][r] = 0.f;
    }

#pragma unroll
    for (int kt = 0; kt < NKT; ++kt) {
      bf16x8 af[4];
      float vs[8];
#pragma unroll
      for (int i = 0; i < 8; ++i) vs[i] = 0.f;

      if constexpr (FIRST) {
        const float* ap = inF + ((size_t)batch * 64 + lr) * CIN + kt * 32 + lk * 8;
#pragma unroll
        for (int mt = 0; mt < 4; ++mt) {
          float4 u0 = *reinterpret_cast<const float4*>(ap + (size_t)mt * 16 * CIN);
          float4 u1 = *reinterpret_cast<const float4*>(ap + (size_t)mt * 16 * CIN + 4);
          float v8[8] = {u0.x, u0.y, u0.z, u0.w, u1.x, u1.y, u1.z, u1.w};
#pragma unroll
          for (int i = 0; i < 8; ++i) {
            vs[i] += v8[i];
            af[mt][i] = (short)f2bf(v8[i]);
          }
        }
      } else {
        const int c0 = kt * 32 + lk * 8;
        const float4 s0 = *reinterpret_cast<const float4*>(&sScale[c0]);
        const float4 s1 = *reinterpret_cast<const float4*>(&sScale[c0 + 4]);
        const float4 h0 = *reinterpret_cast<const float4*>(&sShift[c0]);
        const float4 h1 = *reinterpret_cast<const float4*>(&sShift[c0 + 4]);
        const float scv[8] = {s0.x, s0.y, s0.z, s0.w, s1.x, s1.y, s1.z, s1.w};
        const float shv[8] = {h0.x, h0.y, h0.z, h0.w, h1.x, h1.y, h1.z, h1.w};
        const bf16x8* yb = reinterpret_cast<const bf16x8*>(inB + (size_t)batch * 8192);
#pragma unroll
        for (int mt = 0; mt < 4; ++mt) {
          bf16x8 r16 = yb[kt * 256 + mt * 64 + l];
#pragma unroll
          for (int i = 0; i < 8; ++i) {
            float hv = fmaxf(fmaf(bf2f((unsigned short)r16[i]), scv[i], shv[i]), 0.f);
            vs[i] += hv;
            af[mt][i] = (short)f2bf(hv);
          }
        }
      }

      bf16x8 asum;
#pragma unroll
      for (int i = 0; i < 8; ++i) asum[i] = (short)f2bf(vs[i]);

      const bf16x8* bI = sBu + kt * 512 + l;
#pragma unroll
      for (int ct = 0; ct < 8; ++ct) {
        bf16x8 fI = bI[ct * 64];
#pragma unroll
        for (int mt = 0; mt < 4; ++mt)
          acc[ct][mt] = __builtin_amdgcn_mfma_f32_16x16x32_bf16(af[mt], fI, acc[ct][mt], 0, 0, 0);
      }
      const bf16x8* bJ = bI + NG;
#pragma unroll
      for (int ct = 0; ct < 8; ++ct)
        accJ[ct] = __builtin_amdgcn_mfma_f32_16x16x32_bf16(asum, bJ[ct * 64], accJ[ct], 0, 0, 0);
    }

    // J vector: colsum over accJ's 16 pseudo-rows
    float jv[8];
#pragma unroll
    for (int ct = 0; ct < 8; ++ct) {
      float t = (accJ[ct][0] + accJ[ct][1]) + (accJ[ct][2] + accJ[ct][3]);
      t += __shfl_xor(t, 16);
      t += __shfl_xor(t, 32);
      jv[ct] = t;
    }

    // ---- epilogue: per-mt two-pass 16x72 transpose (wave-private) ----
    unsigned short* myT = &sT[wv][0];
    bf16x8* yo = reinterpret_cast<bf16x8*>(yout + (size_t)batch * 8192);
#pragma unroll
    for (int mt = 0; mt < 4; ++mt) {
#pragma unroll
      for (int cp = 0; cp < 2; ++cp) {
#pragma unroll
        for (int cq = 0; cq < 4; ++cq) {
          const int ct = cp * 4 + cq;
#pragma unroll
          for (int r = 0; r < 4; ++r) {
            float val = acc[ct][mt][r] + jv[ct];
            psum[ct] += val;
            psq[ct]  = fmaf(val, val, psq[ct]);
            myT[(lk * 4 + r) * 72 + cq * 16 + lr] = f2bf(val);
          }
        }
#pragma unroll
        for (int k2 = 0; k2 < 2; ++k2) {
          bf16x8 gd = *reinterpret_cast<const bf16x8*>(&myT[lr * 72 + k2 * 32 + lk * 8]);
          yo[(cp * 2 + k2) * 256 + mt * 64 + l] = gd;
        }
      }
    }
  }

  // ---- stats: shuffle over lk, LDS over waves, one atomicAdd per block ----
#pragma unroll
  for (int ct = 0; ct < 8; ++ct) {
    psum[ct] += __shfl_xor(psum[ct], 16);
    psum[ct] += __shfl_xor(psum[ct], 32);
    psq[ct]  += __shfl_xor(psq[ct], 16);
    psq[ct]  += __shfl_xor(psq[ct], 32);
  }
  if (lk == 0) {
#pragma unroll
    for (int ct = 0; ct < 8; ++ct) {
      sRed[wv][ct * 16 + lr]       = psum[ct];
      sRed[wv][128 + ct * 16 + lr] = psq[ct];
    }
  }
  __syncthreads();
  if (tid < 256) {
    float tot = 0.f;
#pragma unroll
    for (int w2 = 0; w2 < NW; ++w2) tot += sRed[w2][tid];
    atomicAdd(&rawOut[tid], tot);
  }
}

// ---------------------------------------------------------------------------
// Final BN + ReLU + mean over nodes (reads bf16 granules; scsh from raw)
// ---------------------------------------------------------------------------
__global__ __launch_bounds__(256) void pool_k(const unsigned short* __restrict__ y,
                                              const float* __restrict__ raw,
                                              const float* __restrict__ gam,
                                              const float* __restrict__ bet,
                                              float* __restrict__ out)
{
  __shared__ float sYp[64][132];
  __shared__ float sPool[2][DCH];
  const int b = blockIdx.x;
  const int t = threadIdx.x;
  const int wv = t >> 6, l = t & 63;
  const int row = wv * 16 + (l & 15);

#pragma unroll
  for (int kt = 0; kt < 4; ++kt) {
    bf16x8 r16 = *(reinterpret_cast<const bf16x8*>(y + (size_t)b * 8192) + (kt * 256 + t));
    const int feat = kt * 32 + (l >> 4) * 8;
    float4 f0, f1;
    f0.x = bf2f((unsigned short)r16[0]); f0.y = bf2f((unsigned short)r16[1]);
    f0.z = bf2f((unsigned short)r16[2]); f0.w = bf2f((unsigned short)r16[3]);
    f1.x = bf2f((unsigned short)r16[4]); f1.y = bf2f((unsigned short)r16[5]);
    f1.z = bf2f((unsigned short)r16[6]); f1.w = bf2f((unsigned short)r16[7]);
    *reinterpret_cast<float4*>(&sYp[row][feat])     = f0;
    *reinterpret_cast<float4*>(&sYp[row][feat + 4]) = f1;
  }
  __syncthreads();
  {
    const int c = t & 127, rg = t >> 7;
    float mu  = raw[c] * INV_NROWS;
    float var = raw[DCH + c] * INV_NROWS - mu * mu;
    float rr  = rsqrtf(var + 1e-5f);
    float sc  = gam[c] * rr;
    float sh  = fmaf(-mu, sc, bet[c]);
    float s = 0.f;
#pragma unroll 8
    for (int r = rg * 32; r < rg * 32 + 32; ++r)
      s += fmaxf(fmaf(sYp[r][c], sc, sh), 0.f);
    sPool[rg][c] = s;
  }
  __syncthreads();
  if (t < DCH)
    out[(size_t)b * DCH + t] = (sPool[0][t] + sPool[1][t]) * (1.0f / 64.0f);
}

// ---------------------------------------------------------------------------
extern "C" void kernel_launch(void* const* d_in, const int* in_sizes, int n_in,
                              void* d_out, int out_size, void* d_ws, size_t ws_size,
                              hipStream_t stream)
{
  const float* x  = (const float*)d_in[0];
  const float* W1 = (const float*)d_in[1];
  const float* W2 = (const float*)d_in[2];
  const float* W3 = (const float*)d_in[3];
  const float* g1 = (const float*)d_in[4];
  const float* b1 = (const float*)d_in[5];
  const float* g2 = (const float*)d_in[6];
  const float* b2 = (const float*)d_in[7];
  const float* g3 = (const float*)d_in[8];
  const float* b3 = (const float*)d_in[9];
  float* out = (float*)d_out;
  float* ws  = (float*)d_ws;

  Coeffs co;
  {
    double sd  = sqrt(63.0 / 4095.0);
    double av  = exp(-1.0 / sd);
    double deg = 1.0 + 63.0 * av;
    double al  = -(1.0 - av) / deg;
    double be  = -av / deg;
    double ak[5], bk[5];
    ak[0] = 1.0; bk[0] = 0.0;
    ak[1] = al;  bk[1] = be;
    for (int k = 2; k < 5; ++k) {
      ak[k] = 2.0 * al * ak[k - 1] - ak[k - 2];
      bk[k] = 2.0 * (be * ak[k - 1] + (al + 64.0 * be) * bk[k - 1]) - bk[k - 2];
    }
    for (int k = 0; k < 5; ++k) { co.a[k] = (float)ak[k]; co.b[k] = (float)bk[k]; }
  }

  const unsigned short* gr1 = (const unsigned short*)(ws + OFF_G1);
  const unsigned short* gr2 = (const unsigned short*)(ws + OFF_G2);
  const unsigned short* gr3 = (const unsigned short*)(ws + OFF_G3);
  float* raw1 = ws + OFF_RAW;
  float* raw2 = raw1 + 256;
  float* raw3 = raw1 + 512;
  unsigned short* yv = (unsigned short*)(ws + OFF_Y);

  prep_gran<<<64, 256, 0, stream>>>(W1, W2, W3, ws, raw1, co);

  layer_k<256, true,  2, 8><<<256, 512, 0, stream>>>(x, nullptr, yv, gr1,
                                                     nullptr, nullptr, nullptr, raw1);
  layer_k<128, false, 2, 4><<<512, 256, 0, stream>>>(nullptr, yv, yv, gr2,
                                                     raw1, g1, b1, raw2);
  layer_k<128, false, 2, 4><<<512, 256, 0, stream>>>(nullptr, yv, yv, gr3,
                                                     raw2, g2, b2, raw3);
  pool_k<<<BATCH, 256, 0, stream>>>(yv, raw3, g3, b3, out);

  (void)in_sizes; (void)n_in; (void)out_size; (void)ws_size;
}